// Round 1
// baseline (25171.974 us; speedup 1.0000x reference)
//
#include <hip/hip_runtime.h>
#include <hip/hip_bf16.h>

// Problem constants (fixed by the reference)
#define FDIM 128      // F_IN == H == 128
#define G4H  512      // 4*H

// ---------------------------------------------------------------------------
// degree / normalization
// ---------------------------------------------------------------------------
__global__ void deg_kernel(const int* __restrict__ ei, int* __restrict__ deg, int E) {
    int e = blockIdx.x * 256 + threadIdx.x;
    if (e < E) atomicAdd(&deg[ei[E + e]], 1);
}

__global__ void dinv_kernel(const int* __restrict__ deg, float* __restrict__ dinv, int N) {
    int n = blockIdx.x * 256 + threadIdx.x;
    if (n < N) dinv[n] = rsqrtf((float)(deg[n] + 1));   // +1 self-loop
}

// ---------------------------------------------------------------------------
// C[M x 128] = A[M x 128] @ B[128 x 128]   (B is K-major: B[k*128 + j])
// 32 rows / block, K staged in two 64-halves, LDS <= 64KB.
// ---------------------------------------------------------------------------
__global__ __launch_bounds__(256) void gemm_nn(const float* __restrict__ A,
                                               const float* __restrict__ B,
                                               float* __restrict__ C, int M) {
    __shared__ float Bl[64 * 132];
    __shared__ float Al[32][FDIM];
    const int tid = threadIdx.x;
    const int row0 = blockIdx.x * 32;

    for (int i = tid * 4; i < 32 * FDIM; i += 1024) {
        int r = i >> 7, k = i & 127;
        int row = row0 + r;
        float4 v = make_float4(0.f, 0.f, 0.f, 0.f);
        if (row < M) v = *(const float4*)(A + (size_t)row * FDIM + k);
        *(float4*)&Al[r][k] = v;
    }

    const int jg = tid & 31, rg = tid >> 5;
    float acc[4][4] = {};

    for (int kh = 0; kh < 2; ++kh) {
        __syncthreads();
        for (int i = tid * 4; i < 64 * FDIM; i += 1024) {
            int k = i >> 7, j = i & 127;
            *(float4*)&Bl[k * 132 + j] = *(const float4*)(B + (size_t)(kh * 64 + k) * FDIM + j);
        }
        __syncthreads();
        #pragma unroll 4
        for (int k = 0; k < 64; ++k) {
            float4 b4 = *(const float4*)&Bl[k * 132 + jg * 4];
            #pragma unroll
            for (int rr = 0; rr < 4; ++rr) {
                float a = Al[rg * 4 + rr][kh * 64 + k];
                acc[rr][0] += a * b4.x; acc[rr][1] += a * b4.y;
                acc[rr][2] += a * b4.z; acc[rr][3] += a * b4.w;
            }
        }
    }
    #pragma unroll
    for (int rr = 0; rr < 4; ++rr) {
        int row = row0 + rg * 4 + rr;
        if (row < M) {
            float4 v = make_float4(acc[rr][0], acc[rr][1], acc[rr][2], acc[rr][3]);
            *(float4*)(C + (size_t)row * FDIM + jg * 4) = v;
        }
    }
}

// ---------------------------------------------------------------------------
// xg[M x 512] = A[M x 128] @ B^T  (+ b_ih + b_hh), B is [512 x 128] row-major.
// grid.y = 4 chunks of 128 gate-columns. Transposed LDS staging (pad 132).
// ---------------------------------------------------------------------------
__global__ __launch_bounds__(256) void gemm_nt_xg(const float* __restrict__ A,
                                                  const float* __restrict__ B,
                                                  const float* __restrict__ bih,
                                                  const float* __restrict__ bhh,
                                                  float* __restrict__ C, int M) {
    __shared__ float Bl[64 * 132];
    __shared__ float Al[32][FDIM];
    const int tid = threadIdx.x;
    const int row0 = blockIdx.x * 32;
    const int chunk = blockIdx.y;

    for (int i = tid * 4; i < 32 * FDIM; i += 1024) {
        int r = i >> 7, k = i & 127;
        int row = row0 + r;
        float4 v = make_float4(0.f, 0.f, 0.f, 0.f);
        if (row < M) v = *(const float4*)(A + (size_t)row * FDIM + k);
        *(float4*)&Al[r][k] = v;
    }

    const int jg = tid & 31, rg = tid >> 5;
    float acc[4][4] = {};

    for (int kh = 0; kh < 2; ++kh) {
        __syncthreads();
        // load 128 gate-rows x 64 k (transpose into k-major)
        for (int i = tid * 4; i < 128 * 64; i += 1024) {
            int g = i >> 6, kl = i & 63;
            float4 v = *(const float4*)(B + (size_t)(chunk * 128 + g) * FDIM + kh * 64 + kl);
            Bl[(kl + 0) * 132 + g] = v.x;
            Bl[(kl + 1) * 132 + g] = v.y;
            Bl[(kl + 2) * 132 + g] = v.z;
            Bl[(kl + 3) * 132 + g] = v.w;
        }
        __syncthreads();
        #pragma unroll 4
        for (int k = 0; k < 64; ++k) {
            float4 b4 = *(const float4*)&Bl[k * 132 + jg * 4];
            #pragma unroll
            for (int rr = 0; rr < 4; ++rr) {
                float a = Al[rg * 4 + rr][kh * 64 + k];
                acc[rr][0] += a * b4.x; acc[rr][1] += a * b4.y;
                acc[rr][2] += a * b4.z; acc[rr][3] += a * b4.w;
            }
        }
    }
    const int col0 = chunk * 128 + jg * 4;
    float4 bsum = make_float4(bih[col0 + 0] + bhh[col0 + 0],
                              bih[col0 + 1] + bhh[col0 + 1],
                              bih[col0 + 2] + bhh[col0 + 2],
                              bih[col0 + 3] + bhh[col0 + 3]);
    #pragma unroll
    for (int rr = 0; rr < 4; ++rr) {
        int row = row0 + rg * 4 + rr;
        if (row < M) {
            float4 v = make_float4(acc[rr][0] + bsum.x, acc[rr][1] + bsum.y,
                                   acc[rr][2] + bsum.z, acc[rr][3] + bsum.w);
            *(float4*)(C + (size_t)row * G4H + col0) = v;
        }
    }
}

// ---------------------------------------------------------------------------
// GCN aggregation: out[n] = y[n]*dinv[n]^2 + bias   (self-loop + bias init)
// then edge scatter: out[d] += y[s]*dinv[s]*dinv[d]
// ---------------------------------------------------------------------------
__global__ void agg_init(const float* __restrict__ y, const float* __restrict__ dinv,
                         const float* __restrict__ bias, float* __restrict__ o, int N) {
    int idx = blockIdx.x * 256 + threadIdx.x;
    int n = idx >> 5, cc = (idx & 31) * 4;
    if (n >= N) return;
    float s = dinv[n]; s = s * s;
    float4 v = *(const float4*)(y + (size_t)n * FDIM + cc);
    float4 b = *(const float4*)(bias + cc);
    float4 r = make_float4(v.x * s + b.x, v.y * s + b.y, v.z * s + b.z, v.w * s + b.w);
    *(float4*)(o + (size_t)n * FDIM + cc) = r;
}

__global__ void agg_edges(const float* __restrict__ y, const int* __restrict__ ei,
                          const float* __restrict__ dinv, float* __restrict__ o, int E) {
    int idx = blockIdx.x * 256 + threadIdx.x;
    int e = idx >> 5, cc = (idx & 31) * 4;
    if (e >= E) return;
    int s = ei[e], d = ei[E + e];
    float nrm = dinv[s] * dinv[d];
    float4 v = *(const float4*)(y + (size_t)s * FDIM + cc);
    float* dst = o + (size_t)d * FDIM + cc;
    atomicAdd(dst + 0, v.x * nrm);
    atomicAdd(dst + 1, v.y * nrm);
    atomicAdd(dst + 2, v.z * nrm);
    atomicAdd(dst + 3, v.w * nrm);
}

__global__ void relu_kernel(float* __restrict__ x, int n4) {
    int i = blockIdx.x * 256 + threadIdx.x;
    if (i < n4) {
        float4 v = ((float4*)x)[i];
        v.x = fmaxf(v.x, 0.f); v.y = fmaxf(v.y, 0.f);
        v.z = fmaxf(v.z, 0.f); v.w = fmaxf(v.w, 0.f);
        ((float4*)x)[i] = v;
    }
}

// ---------------------------------------------------------------------------
// LSTM: sequential over steps. 1 block x 512 threads (thread j = gate row j).
// w_hh row held in 128 registers/thread; h broadcast via LDS.
// ---------------------------------------------------------------------------
__global__ __launch_bounds__(512) void lstm_kernel(const float* __restrict__ xg,
                                                   const float* __restrict__ whh,
                                                   float* __restrict__ hs, int T) {
    __shared__ float hl[FDIM];
    __shared__ float gl[G4H];
    const int j = threadIdx.x;

    float w[FDIM];
    #pragma unroll
    for (int k = 0; k < FDIM; k += 4) {
        float4 a = *(const float4*)(whh + (size_t)j * FDIM + k);
        w[k] = a.x; w[k + 1] = a.y; w[k + 2] = a.z; w[k + 3] = a.w;
    }
    if (j < FDIM) hl[j] = 0.f;
    float c = 0.f;
    float x0 = xg[j];
    float x1 = xg[G4H + j];
    const bool is_g = ((j >> 7) == 2);   // wave-uniform (128-aligned groups)
    __syncthreads();

    for (int t = 0; t < T; ++t) {
        float a0 = x0, a1 = 0.f, a2 = 0.f, a3 = 0.f;
        x0 = x1;
        if (t + 2 < T) x1 = xg[(size_t)(t + 2) * G4H + j];   // 2-deep prefetch
        #pragma unroll
        for (int k = 0; k < FDIM; k += 16) {
            float4 hA = *(const float4*)(hl + k);
            float4 hB = *(const float4*)(hl + k + 4);
            float4 hC = *(const float4*)(hl + k + 8);
            float4 hD = *(const float4*)(hl + k + 12);
            a0 += w[k +  0] * hA.x + w[k +  1] * hA.y + w[k +  2] * hA.z + w[k +  3] * hA.w;
            a1 += w[k +  4] * hB.x + w[k +  5] * hB.y + w[k +  6] * hB.z + w[k +  7] * hB.w;
            a2 += w[k +  8] * hC.x + w[k +  9] * hC.y + w[k + 10] * hC.z + w[k + 11] * hC.w;
            a3 += w[k + 12] * hD.x + w[k + 13] * hD.y + w[k + 14] * hD.z + w[k + 15] * hD.w;
        }
        float acc = (a0 + a1) + (a2 + a3);
        float act;
        if (is_g) act = 1.f - 2.f / (1.f + __expf(2.f * acc));   // tanh
        else      act = 1.f / (1.f + __expf(-acc));              // sigmoid
        gl[j] = act;
        __syncthreads();
        if (j < FDIM) {
            float ig = gl[j], fg = gl[FDIM + j], gg = gl[2 * FDIM + j], og = gl[3 * FDIM + j];
            c = fg * c + ig * gg;
            float e2 = __expf(2.f * c);
            float th = 1.f - 2.f / (1.f + e2);
            float h = og * th;
            hl[j] = h;
            hs[(size_t)t * FDIM + j] = h;
        }
        __syncthreads();
    }
}

// ---------------------------------------------------------------------------
// out[M x 12] = hs[M x 128] @ w_fc^T + b_fc   (w_fc is [12 x 128])
// ---------------------------------------------------------------------------
__global__ __launch_bounds__(256) void fc_kernel(const float* __restrict__ hs,
                                                 const float* __restrict__ wfc,
                                                 const float* __restrict__ bfc,
                                                 float* __restrict__ out, int M) {
    __shared__ float wl[12 * FDIM];
    __shared__ float bl[12];
    const int tid = threadIdx.x;
    for (int i = tid; i < 12 * FDIM / 4; i += 256)
        ((float4*)wl)[i] = ((const float4*)wfc)[i];
    if (tid < 12) bl[tid] = bfc[tid];
    __syncthreads();

    int i = blockIdx.x * 256 + tid;
    if (i >= M) return;
    const float* hrow = hs + (size_t)i * FDIM;
    float acc[12];
    #pragma unroll
    for (int t = 0; t < 12; ++t) acc[t] = bl[t];
    for (int k = 0; k < FDIM; k += 4) {
        float4 h4 = *(const float4*)(hrow + k);
        #pragma unroll
        for (int t = 0; t < 12; ++t) {
            acc[t] += h4.x * wl[t * FDIM + k] + h4.y * wl[t * FDIM + k + 1]
                    + h4.z * wl[t * FDIM + k + 2] + h4.w * wl[t * FDIM + k + 3];
        }
    }
    #pragma unroll
    for (int t = 0; t < 12; ++t) out[(size_t)i * 12 + t] = acc[t];
}

// ---------------------------------------------------------------------------
extern "C" void kernel_launch(void* const* d_in, const int* in_sizes, int n_in,
                              void* d_out, int out_size, void* d_ws, size_t ws_size,
                              hipStream_t stream) {
    const float* x    = (const float*)d_in[0];
    const int*   ei   = (const int*)  d_in[1];
    const float* W1   = (const float*)d_in[2];
    const float* b1   = (const float*)d_in[3];
    const float* W2   = (const float*)d_in[4];
    const float* b2   = (const float*)d_in[5];
    const float* w_ih = (const float*)d_in[6];
    const float* w_hh = (const float*)d_in[7];
    const float* b_ih = (const float*)d_in[8];
    const float* b_hh = (const float*)d_in[9];
    const float* w_fc = (const float*)d_in[10];
    const float* b_fc = (const float*)d_in[11];

    const int N = in_sizes[0] / FDIM;     // 20000
    const int E = in_sizes[1] / 2;        // 1280000

    float* ws   = (float*)d_ws;
    int*   deg  = (int*)ws;               // [0, 20480) ints
    float* dinv = ws + 20480;
    float* hB   = ws + 40960;             // h2: N*128
    float* big  = hB + (size_t)N * FDIM;  // xg region (N*512), aliases y/hA
    float* y    = big;                    // N*128 (dead before xg written)
    float* hA   = big + (size_t)N * FDIM; // h1   (dead before xg written)
    float* xg   = big;                    // N*512
    float* hs   = big + (size_t)N * G4H;  // N*128

    hipMemsetAsync(deg, 0, (size_t)N * sizeof(int), stream);
    deg_kernel<<<(E + 255) / 256, 256, 0, stream>>>(ei, deg, E);
    dinv_kernel<<<(N + 255) / 256, 256, 0, stream>>>(deg, dinv, N);

    const int gblocks = (N + 31) / 32;
    // layer 1
    gemm_nn<<<gblocks, 256, 0, stream>>>(x, W1, y, N);
    agg_init<<<(N * 32 + 255) / 256, 256, 0, stream>>>(y, dinv, b1, hA, N);
    agg_edges<<<(E * 32 + 255) / 256, 256, 0, stream>>>(y, ei, dinv, hA, E);
    relu_kernel<<<(N * 32 + 255) / 256, 256, 0, stream>>>(hA, N * 32);
    // layer 2
    gemm_nn<<<gblocks, 256, 0, stream>>>(hA, W2, y, N);
    agg_init<<<(N * 32 + 255) / 256, 256, 0, stream>>>(y, dinv, b2, hB, N);
    agg_edges<<<(E * 32 + 255) / 256, 256, 0, stream>>>(y, ei, dinv, hB, E);
    relu_kernel<<<(N * 32 + 255) / 256, 256, 0, stream>>>(hB, N * 32);
    // LSTM input projection
    gemm_nt_xg<<<dim3(gblocks, 4), 256, 0, stream>>>(hB, w_ih, b_ih, b_hh, xg, N);
    // sequential LSTM (single CU — the critical path)
    lstm_kernel<<<1, 512, 0, stream>>>(xg, w_hh, hs, N);
    // final projection
    fc_kernel<<<(N + 255) / 256, 256, 0, stream>>>(hs, w_fc, b_fc, (float*)d_out, N);
}

// Round 2
// 24552.463 us; speedup vs baseline: 1.0252x; 1.0252x over previous
//
#include <hip/hip_runtime.h>
#include <hip/hip_bf16.h>

// Problem constants (fixed by the reference)
#define FDIM 128      // F_IN == H == 128
#define G4H  512      // 4*H

typedef float f32x2 __attribute__((ext_vector_type(2)));

// ---------------------------------------------------------------------------
// degree / normalization
// ---------------------------------------------------------------------------
__global__ void deg_kernel(const int* __restrict__ ei, int* __restrict__ deg, int E) {
    int e = blockIdx.x * 256 + threadIdx.x;
    if (e < E) atomicAdd(&deg[ei[E + e]], 1);
}

__global__ void dinv_kernel(const int* __restrict__ deg, float* __restrict__ dinv, int N) {
    int n = blockIdx.x * 256 + threadIdx.x;
    if (n < N) dinv[n] = rsqrtf((float)(deg[n] + 1));   // +1 self-loop
}

// ---------------------------------------------------------------------------
// C[M x 128] = A[M x 128] @ B[128 x 128]   (B is K-major: B[k*128 + j])
// ---------------------------------------------------------------------------
__global__ __launch_bounds__(256) void gemm_nn(const float* __restrict__ A,
                                               const float* __restrict__ B,
                                               float* __restrict__ C, int M) {
    __shared__ float Bl[64 * 132];
    __shared__ float Al[32][FDIM];
    const int tid = threadIdx.x;
    const int row0 = blockIdx.x * 32;

    for (int i = tid * 4; i < 32 * FDIM; i += 1024) {
        int r = i >> 7, k = i & 127;
        int row = row0 + r;
        float4 v = make_float4(0.f, 0.f, 0.f, 0.f);
        if (row < M) v = *(const float4*)(A + (size_t)row * FDIM + k);
        *(float4*)&Al[r][k] = v;
    }

    const int jg = tid & 31, rg = tid >> 5;
    float acc[4][4] = {};

    for (int kh = 0; kh < 2; ++kh) {
        __syncthreads();
        for (int i = tid * 4; i < 64 * FDIM; i += 1024) {
            int k = i >> 7, j = i & 127;
            *(float4*)&Bl[k * 132 + j] = *(const float4*)(B + (size_t)(kh * 64 + k) * FDIM + j);
        }
        __syncthreads();
        #pragma unroll 4
        for (int k = 0; k < 64; ++k) {
            float4 b4 = *(const float4*)&Bl[k * 132 + jg * 4];
            #pragma unroll
            for (int rr = 0; rr < 4; ++rr) {
                float a = Al[rg * 4 + rr][kh * 64 + k];
                acc[rr][0] += a * b4.x; acc[rr][1] += a * b4.y;
                acc[rr][2] += a * b4.z; acc[rr][3] += a * b4.w;
            }
        }
    }
    #pragma unroll
    for (int rr = 0; rr < 4; ++rr) {
        int row = row0 + rg * 4 + rr;
        if (row < M) {
            float4 v = make_float4(acc[rr][0], acc[rr][1], acc[rr][2], acc[rr][3]);
            *(float4*)(C + (size_t)row * FDIM + jg * 4) = v;
        }
    }
}

// ---------------------------------------------------------------------------
// xg[M x 512] = A[M x 128] @ B^T  (+ b_ih + b_hh), B is [512 x 128] row-major.
// ---------------------------------------------------------------------------
__global__ __launch_bounds__(256) void gemm_nt_xg(const float* __restrict__ A,
                                                  const float* __restrict__ B,
                                                  const float* __restrict__ bih,
                                                  const float* __restrict__ bhh,
                                                  float* __restrict__ C, int M) {
    __shared__ float Bl[64 * 132];
    __shared__ float Al[32][FDIM];
    const int tid = threadIdx.x;
    const int row0 = blockIdx.x * 32;
    const int chunk = blockIdx.y;

    for (int i = tid * 4; i < 32 * FDIM; i += 1024) {
        int r = i >> 7, k = i & 127;
        int row = row0 + r;
        float4 v = make_float4(0.f, 0.f, 0.f, 0.f);
        if (row < M) v = *(const float4*)(A + (size_t)row * FDIM + k);
        *(float4*)&Al[r][k] = v;
    }

    const int jg = tid & 31, rg = tid >> 5;
    float acc[4][4] = {};

    for (int kh = 0; kh < 2; ++kh) {
        __syncthreads();
        for (int i = tid * 4; i < 128 * 64; i += 1024) {
            int g = i >> 6, kl = i & 63;
            float4 v = *(const float4*)(B + (size_t)(chunk * 128 + g) * FDIM + kh * 64 + kl);
            Bl[(kl + 0) * 132 + g] = v.x;
            Bl[(kl + 1) * 132 + g] = v.y;
            Bl[(kl + 2) * 132 + g] = v.z;
            Bl[(kl + 3) * 132 + g] = v.w;
        }
        __syncthreads();
        #pragma unroll 4
        for (int k = 0; k < 64; ++k) {
            float4 b4 = *(const float4*)&Bl[k * 132 + jg * 4];
            #pragma unroll
            for (int rr = 0; rr < 4; ++rr) {
                float a = Al[rg * 4 + rr][kh * 64 + k];
                acc[rr][0] += a * b4.x; acc[rr][1] += a * b4.y;
                acc[rr][2] += a * b4.z; acc[rr][3] += a * b4.w;
            }
        }
    }
    const int col0 = chunk * 128 + jg * 4;
    float4 bsum = make_float4(bih[col0 + 0] + bhh[col0 + 0],
                              bih[col0 + 1] + bhh[col0 + 1],
                              bih[col0 + 2] + bhh[col0 + 2],
                              bih[col0 + 3] + bhh[col0 + 3]);
    #pragma unroll
    for (int rr = 0; rr < 4; ++rr) {
        int row = row0 + rg * 4 + rr;
        if (row < M) {
            float4 v = make_float4(acc[rr][0] + bsum.x, acc[rr][1] + bsum.y,
                                   acc[rr][2] + bsum.z, acc[rr][3] + bsum.w);
            *(float4*)(C + (size_t)row * G4H + col0) = v;
        }
    }
}

// ---------------------------------------------------------------------------
// GCN aggregation
// ---------------------------------------------------------------------------
__global__ void agg_init(const float* __restrict__ y, const float* __restrict__ dinv,
                         const float* __restrict__ bias, float* __restrict__ o, int N) {
    int idx = blockIdx.x * 256 + threadIdx.x;
    int n = idx >> 5, cc = (idx & 31) * 4;
    if (n >= N) return;
    float s = dinv[n]; s = s * s;
    float4 v = *(const float4*)(y + (size_t)n * FDIM + cc);
    float4 b = *(const float4*)(bias + cc);
    float4 r = make_float4(v.x * s + b.x, v.y * s + b.y, v.z * s + b.z, v.w * s + b.w);
    *(float4*)(o + (size_t)n * FDIM + cc) = r;
}

__global__ void agg_edges(const float* __restrict__ y, const int* __restrict__ ei,
                          const float* __restrict__ dinv, float* __restrict__ o, int E) {
    int idx = blockIdx.x * 256 + threadIdx.x;
    int e = idx >> 5, cc = (idx & 31) * 4;
    if (e >= E) return;
    int s = ei[e], d = ei[E + e];
    float nrm = dinv[s] * dinv[d];
    float4 v = *(const float4*)(y + (size_t)s * FDIM + cc);
    float* dst = o + (size_t)d * FDIM + cc;
    atomicAdd(dst + 0, v.x * nrm);
    atomicAdd(dst + 1, v.y * nrm);
    atomicAdd(dst + 2, v.z * nrm);
    atomicAdd(dst + 3, v.w * nrm);
}

__global__ void relu_kernel(float* __restrict__ x, int n4) {
    int i = blockIdx.x * 256 + threadIdx.x;
    if (i < n4) {
        float4 v = ((float4*)x)[i];
        v.x = fmaxf(v.x, 0.f); v.y = fmaxf(v.y, 0.f);
        v.z = fmaxf(v.z, 0.f); v.w = fmaxf(v.w, 0.f);
        ((float4*)x)[i] = v;
    }
}

// ---------------------------------------------------------------------------
// LSTM v2: 512 threads. thread (s=t>>7, j=t&127) computes all 4 gates of
// hidden index j over K-slice [32s, 32s+32). Weights resident: 128 VGPRs
// (amdgpu_waves_per_eu(2,2) -> 256-VGPR budget, no load sinking).
// h broadcast via v_readlane -> SGPR pair -> v_pk_fma_f32 (no LDS broadcast).
// Activation/c-update replicated across the 4 slice groups (identical math).
// ---------------------------------------------------------------------------
__global__ void __launch_bounds__(512)
__attribute__((amdgpu_waves_per_eu(2, 2)))
lstm_kernel(const float* __restrict__ xg, const float* __restrict__ whh,
            float* __restrict__ hs, int T) {
    __shared__ float hl[FDIM];
    __shared__ float part[4 * G4H / 4 * 4];   // 4 slices x 128 j x 4 gates = 2048 floats
    const int t = threadIdx.x;
    const int j = t & 127;
    const int s = __builtin_amdgcn_readfirstlane(t >> 7);  // wave-uniform slice id
    const int lane = t & 63;

    // Load weights once: rows g*128+j, cols [32s, 32s+32)  -> 128 VGPRs
    f32x2 w2[4][16];
    {
        const float* wbase = whh + (size_t)j * FDIM + s * 32;
        #pragma unroll
        for (int g = 0; g < 4; ++g) {
            const float* wr = wbase + (size_t)g * FDIM * FDIM;
            #pragma unroll
            for (int m = 0; m < 16; ++m)
                w2[g][m] = *(const f32x2*)(wr + 2 * m);
        }
    }

    if (t < FDIM) hl[t] = 0.f;
    float c = 0.f;
    float xv0 = xg[t];
    float xv1 = xg[G4H + t];
    __syncthreads();

    for (int step = 0; step < T; ++step) {
        // refresh local distributed h: lane holds h[2*lane], h[2*lane+1]
        f32x2 hloc = *(const f32x2*)(hl + 2 * lane);
        float xcur = xv0;
        xv0 = xv1;
        if (step + 2 < T) xv1 = xg[(size_t)(step + 2) * G4H + t];

        f32x2 acc0 = {0.f, 0.f}, acc1 = {0.f, 0.f}, acc2 = {0.f, 0.f}, acc3 = {0.f, 0.f};
        #pragma unroll
        for (int m = 0; m < 16; ++m) {
            int p = s * 16 + m;   // source lane holding h[2p], h[2p+1]
            f32x2 hp;
            hp.x = __int_as_float(__builtin_amdgcn_readlane(__float_as_int(hloc.x), p));
            hp.y = __int_as_float(__builtin_amdgcn_readlane(__float_as_int(hloc.y), p));
            asm("v_pk_fma_f32 %0, %1, %2, %0" : "+v"(acc0) : "v"(w2[0][m]), "s"(hp));
            asm("v_pk_fma_f32 %0, %1, %2, %0" : "+v"(acc1) : "v"(w2[1][m]), "s"(hp));
            asm("v_pk_fma_f32 %0, %1, %2, %0" : "+v"(acc2) : "v"(w2[2][m]), "s"(hp));
            asm("v_pk_fma_f32 %0, %1, %2, %0" : "+v"(acc3) : "v"(w2[3][m]), "s"(hp));
        }
        // horizontal add + fold xg (this thread's xg column t = gate s, index j)
        float4 pw;
        pw.x = acc0.x + acc0.y + (s == 0 ? xcur : 0.f);
        pw.y = acc1.x + acc1.y + (s == 1 ? xcur : 0.f);
        pw.z = acc2.x + acc2.y + (s == 2 ? xcur : 0.f);
        pw.w = acc3.x + acc3.y + (s == 3 ? xcur : 0.f);
        *(float4*)(part + s * 512 + j * 4) = pw;
        __syncthreads();

        // combine partials (replicated across slice groups)
        float4 q0 = *(const float4*)(part + 0 * 512 + j * 4);
        float4 q1 = *(const float4*)(part + 1 * 512 + j * 4);
        float4 q2 = *(const float4*)(part + 2 * 512 + j * 4);
        float4 q3 = *(const float4*)(part + 3 * 512 + j * 4);
        float gi = (q0.x + q1.x) + (q2.x + q3.x);
        float gf = (q0.y + q1.y) + (q2.y + q3.y);
        float gg = (q0.z + q1.z) + (q2.z + q3.z);
        float go = (q0.w + q1.w) + (q2.w + q3.w);
        gi = 1.f / (1.f + __expf(-gi));
        gf = 1.f / (1.f + __expf(-gf));
        gg = 1.f - 2.f / (1.f + __expf(2.f * gg));
        go = 1.f / (1.f + __expf(-go));
        c = gf * c + gi * gg;
        float th = 1.f - 2.f / (1.f + __expf(2.f * c));
        float h = go * th;
        if (s == 0) {
            hl[j] = h;
            hs[(size_t)step * FDIM + j] = h;
        }
        __syncthreads();
    }
}

// ---------------------------------------------------------------------------
// out[M x 12] = hs[M x 128] @ w_fc^T + b_fc
// ---------------------------------------------------------------------------
__global__ __launch_bounds__(256) void fc_kernel(const float* __restrict__ hs,
                                                 const float* __restrict__ wfc,
                                                 const float* __restrict__ bfc,
                                                 float* __restrict__ out, int M) {
    __shared__ float wl[12 * FDIM];
    __shared__ float bl[12];
    const int tid = threadIdx.x;
    for (int i = tid; i < 12 * FDIM / 4; i += 256)
        ((float4*)wl)[i] = ((const float4*)wfc)[i];
    if (tid < 12) bl[tid] = bfc[tid];
    __syncthreads();

    int i = blockIdx.x * 256 + tid;
    if (i >= M) return;
    const float* hrow = hs + (size_t)i * FDIM;
    float acc[12];
    #pragma unroll
    for (int t = 0; t < 12; ++t) acc[t] = bl[t];
    for (int k = 0; k < FDIM; k += 4) {
        float4 h4 = *(const float4*)(hrow + k);
        #pragma unroll
        for (int t = 0; t < 12; ++t) {
            acc[t] += h4.x * wl[t * FDIM + k] + h4.y * wl[t * FDIM + k + 1]
                    + h4.z * wl[t * FDIM + k + 2] + h4.w * wl[t * FDIM + k + 3];
        }
    }
    #pragma unroll
    for (int t = 0; t < 12; ++t) out[(size_t)i * 12 + t] = acc[t];
}

// ---------------------------------------------------------------------------
extern "C" void kernel_launch(void* const* d_in, const int* in_sizes, int n_in,
                              void* d_out, int out_size, void* d_ws, size_t ws_size,
                              hipStream_t stream) {
    const float* x    = (const float*)d_in[0];
    const int*   ei   = (const int*)  d_in[1];
    const float* W1   = (const float*)d_in[2];
    const float* b1   = (const float*)d_in[3];
    const float* W2   = (const float*)d_in[4];
    const float* b2   = (const float*)d_in[5];
    const float* w_ih = (const float*)d_in[6];
    const float* w_hh = (const float*)d_in[7];
    const float* b_ih = (const float*)d_in[8];
    const float* b_hh = (const float*)d_in[9];
    const float* w_fc = (const float*)d_in[10];
    const float* b_fc = (const float*)d_in[11];

    const int N = in_sizes[0] / FDIM;     // 20000
    const int E = in_sizes[1] / 2;        // 1280000

    float* ws   = (float*)d_ws;
    int*   deg  = (int*)ws;               // [0, 20480) ints
    float* dinv = ws + 20480;
    float* hB   = ws + 40960;             // h2: N*128
    float* big  = hB + (size_t)N * FDIM;  // xg region (N*512), aliases y/hA
    float* y    = big;                    // N*128 (dead before xg written)
    float* hA   = big + (size_t)N * FDIM; // h1   (dead before xg written)
    float* xg   = big;                    // N*512
    float* hs   = big + (size_t)N * G4H;  // N*128

    hipMemsetAsync(deg, 0, (size_t)N * sizeof(int), stream);
    deg_kernel<<<(E + 255) / 256, 256, 0, stream>>>(ei, deg, E);
    dinv_kernel<<<(N + 255) / 256, 256, 0, stream>>>(deg, dinv, N);

    const int gblocks = (N + 31) / 32;
    // layer 1
    gemm_nn<<<gblocks, 256, 0, stream>>>(x, W1, y, N);
    agg_init<<<(N * 32 + 255) / 256, 256, 0, stream>>>(y, dinv, b1, hA, N);
    agg_edges<<<(E * 32 + 255) / 256, 256, 0, stream>>>(y, ei, dinv, hA, E);
    relu_kernel<<<(N * 32 + 255) / 256, 256, 0, stream>>>(hA, N * 32);
    // layer 2
    gemm_nn<<<gblocks, 256, 0, stream>>>(hA, W2, y, N);
    agg_init<<<(N * 32 + 255) / 256, 256, 0, stream>>>(y, dinv, b2, hB, N);
    agg_edges<<<(E * 32 + 255) / 256, 256, 0, stream>>>(y, ei, dinv, hB, E);
    relu_kernel<<<(N * 32 + 255) / 256, 256, 0, stream>>>(hB, N * 32);
    // LSTM input projection
    gemm_nt_xg<<<dim3(gblocks, 4), 256, 0, stream>>>(hB, w_ih, b_ih, b_hh, xg, N);
    // sequential LSTM (single CU — the critical path)
    lstm_kernel<<<1, 512, 0, stream>>>(xg, w_hh, hs, N);
    // final projection
    fc_kernel<<<(N + 255) / 256, 256, 0, stream>>>(hs, w_fc, b_fc, (float*)d_out, N);
}

// Round 3
// 24473.604 us; speedup vs baseline: 1.0285x; 1.0032x over previous
//
#include <hip/hip_runtime.h>
#include <hip/hip_bf16.h>

// Problem constants (fixed by the reference)
#define FDIM 128      // F_IN == H == 128
#define G4H  512      // 4*H

typedef float f32x2 __attribute__((ext_vector_type(2)));

// ---------------------------------------------------------------------------
// degree / normalization
// ---------------------------------------------------------------------------
__global__ void deg_kernel(const int* __restrict__ ei, int* __restrict__ deg, int E) {
    int e = blockIdx.x * 256 + threadIdx.x;
    if (e < E) atomicAdd(&deg[ei[E + e]], 1);
}

__global__ void dinv_kernel(const int* __restrict__ deg, float* __restrict__ dinv, int N) {
    int n = blockIdx.x * 256 + threadIdx.x;
    if (n < N) dinv[n] = rsqrtf((float)(deg[n] + 1));   // +1 self-loop
}

// ---------------------------------------------------------------------------
// C[M x 128] = A[M x 128] @ B[128 x 128]   (B is K-major: B[k*128 + j])
// ---------------------------------------------------------------------------
__global__ __launch_bounds__(256) void gemm_nn(const float* __restrict__ A,
                                               const float* __restrict__ B,
                                               float* __restrict__ C, int M) {
    __shared__ float Bl[64 * 132];
    __shared__ float Al[32][FDIM];
    const int tid = threadIdx.x;
    const int row0 = blockIdx.x * 32;

    for (int i = tid * 4; i < 32 * FDIM; i += 1024) {
        int r = i >> 7, k = i & 127;
        int row = row0 + r;
        float4 v = make_float4(0.f, 0.f, 0.f, 0.f);
        if (row < M) v = *(const float4*)(A + (size_t)row * FDIM + k);
        *(float4*)&Al[r][k] = v;
    }

    const int jg = tid & 31, rg = tid >> 5;
    float acc[4][4] = {};

    for (int kh = 0; kh < 2; ++kh) {
        __syncthreads();
        for (int i = tid * 4; i < 64 * FDIM; i += 1024) {
            int k = i >> 7, j = i & 127;
            *(float4*)&Bl[k * 132 + j] = *(const float4*)(B + (size_t)(kh * 64 + k) * FDIM + j);
        }
        __syncthreads();
        #pragma unroll 4
        for (int k = 0; k < 64; ++k) {
            float4 b4 = *(const float4*)&Bl[k * 132 + jg * 4];
            #pragma unroll
            for (int rr = 0; rr < 4; ++rr) {
                float a = Al[rg * 4 + rr][kh * 64 + k];
                acc[rr][0] += a * b4.x; acc[rr][1] += a * b4.y;
                acc[rr][2] += a * b4.z; acc[rr][3] += a * b4.w;
            }
        }
    }
    #pragma unroll
    for (int rr = 0; rr < 4; ++rr) {
        int row = row0 + rg * 4 + rr;
        if (row < M) {
            float4 v = make_float4(acc[rr][0], acc[rr][1], acc[rr][2], acc[rr][3]);
            *(float4*)(C + (size_t)row * FDIM + jg * 4) = v;
        }
    }
}

// ---------------------------------------------------------------------------
// xg[M x 512] = A[M x 128] @ B^T  (+ b_ih + b_hh), B is [512 x 128] row-major.
// ---------------------------------------------------------------------------
__global__ __launch_bounds__(256) void gemm_nt_xg(const float* __restrict__ A,
                                                  const float* __restrict__ B,
                                                  const float* __restrict__ bih,
                                                  const float* __restrict__ bhh,
                                                  float* __restrict__ C, int M) {
    __shared__ float Bl[64 * 132];
    __shared__ float Al[32][FDIM];
    const int tid = threadIdx.x;
    const int row0 = blockIdx.x * 32;
    const int chunk = blockIdx.y;

    for (int i = tid * 4; i < 32 * FDIM; i += 1024) {
        int r = i >> 7, k = i & 127;
        int row = row0 + r;
        float4 v = make_float4(0.f, 0.f, 0.f, 0.f);
        if (row < M) v = *(const float4*)(A + (size_t)row * FDIM + k);
        *(float4*)&Al[r][k] = v;
    }

    const int jg = tid & 31, rg = tid >> 5;
    float acc[4][4] = {};

    for (int kh = 0; kh < 2; ++kh) {
        __syncthreads();
        for (int i = tid * 4; i < 128 * 64; i += 1024) {
            int g = i >> 6, kl = i & 63;
            float4 v = *(const float4*)(B + (size_t)(chunk * 128 + g) * FDIM + kh * 64 + kl);
            Bl[(kl + 0) * 132 + g] = v.x;
            Bl[(kl + 1) * 132 + g] = v.y;
            Bl[(kl + 2) * 132 + g] = v.z;
            Bl[(kl + 3) * 132 + g] = v.w;
        }
        __syncthreads();
        #pragma unroll 4
        for (int k = 0; k < 64; ++k) {
            float4 b4 = *(const float4*)&Bl[k * 132 + jg * 4];
            #pragma unroll
            for (int rr = 0; rr < 4; ++rr) {
                float a = Al[rg * 4 + rr][kh * 64 + k];
                acc[rr][0] += a * b4.x; acc[rr][1] += a * b4.y;
                acc[rr][2] += a * b4.z; acc[rr][3] += a * b4.w;
            }
        }
    }
    const int col0 = chunk * 128 + jg * 4;
    float4 bsum = make_float4(bih[col0 + 0] + bhh[col0 + 0],
                              bih[col0 + 1] + bhh[col0 + 1],
                              bih[col0 + 2] + bhh[col0 + 2],
                              bih[col0 + 3] + bhh[col0 + 3]);
    #pragma unroll
    for (int rr = 0; rr < 4; ++rr) {
        int row = row0 + rg * 4 + rr;
        if (row < M) {
            float4 v = make_float4(acc[rr][0] + bsum.x, acc[rr][1] + bsum.y,
                                   acc[rr][2] + bsum.z, acc[rr][3] + bsum.w);
            *(float4*)(C + (size_t)row * G4H + col0) = v;
        }
    }
}

// ---------------------------------------------------------------------------
// GCN aggregation
// ---------------------------------------------------------------------------
__global__ void agg_init(const float* __restrict__ y, const float* __restrict__ dinv,
                         const float* __restrict__ bias, float* __restrict__ o, int N) {
    int idx = blockIdx.x * 256 + threadIdx.x;
    int n = idx >> 5, cc = (idx & 31) * 4;
    if (n >= N) return;
    float s = dinv[n]; s = s * s;
    float4 v = *(const float4*)(y + (size_t)n * FDIM + cc);
    float4 b = *(const float4*)(bias + cc);
    float4 r = make_float4(v.x * s + b.x, v.y * s + b.y, v.z * s + b.z, v.w * s + b.w);
    *(float4*)(o + (size_t)n * FDIM + cc) = r;
}

__global__ void agg_edges(const float* __restrict__ y, const int* __restrict__ ei,
                          const float* __restrict__ dinv, float* __restrict__ o, int E) {
    int idx = blockIdx.x * 256 + threadIdx.x;
    int e = idx >> 5, cc = (idx & 31) * 4;
    if (e >= E) return;
    int s = ei[e], d = ei[E + e];
    float nrm = dinv[s] * dinv[d];
    float4 v = *(const float4*)(y + (size_t)s * FDIM + cc);
    float* dst = o + (size_t)d * FDIM + cc;
    atomicAdd(dst + 0, v.x * nrm);
    atomicAdd(dst + 1, v.y * nrm);
    atomicAdd(dst + 2, v.z * nrm);
    atomicAdd(dst + 3, v.w * nrm);
}

__global__ void relu_kernel(float* __restrict__ x, int n4) {
    int i = blockIdx.x * 256 + threadIdx.x;
    if (i < n4) {
        float4 v = ((float4*)x)[i];
        v.x = fmaxf(v.x, 0.f); v.y = fmaxf(v.y, 0.f);
        v.z = fmaxf(v.z, 0.f); v.w = fmaxf(v.w, 0.f);
        ((float4*)x)[i] = v;
    }
}

// ---------------------------------------------------------------------------
// LSTM v3: same topology as v2 (thread (s=t>>7, j=t&127) does 4 gate rows of
// index j over K-slice [32s,32s+32); h via readlane->SGPR; pk_fma), but the
// 64 f32x2 weights are loaded with asm volatile global_load_dwordx2 so the
// compiler CANNOT sink them into the t-loop (v1/v2 re-streamed 256 KB/step
// from L2 = ~2050 cyc/step). __launch_bounds__(512,2) -> 256-VGPR budget.
// ---------------------------------------------------------------------------
__global__ void __launch_bounds__(512, 2)
lstm_kernel(const float* __restrict__ xg, const float* __restrict__ whh,
            float* __restrict__ hs, int T) {
    __shared__ float hl[FDIM];
    __shared__ float part[2048];   // 4 slices x 128 j x 4 gates
    const int t = threadIdx.x;
    const int j = t & 127;
    const int s = __builtin_amdgcn_readfirstlane(t >> 7);  // wave-uniform slice id
    const int lane = t & 63;

    // Pinned weight load: rows g*128+j, cols [32s,32s+32) -> 128 VGPRs.
    // asm volatile cannot be sunk/rematerialized by the compiler.
    f32x2 w2[4][16];
    #pragma unroll
    for (int g = 0; g < 4; ++g) {
        const float* wr = whh + (size_t)(g * FDIM + j) * FDIM + s * 32;
        #pragma unroll
        for (int m = 0; m < 16; ++m)
            asm volatile("global_load_dwordx2 %0, %1, off"
                         : "=v"(w2[g][m]) : "v"(wr + 2 * m));
    }
    asm volatile("s_waitcnt vmcnt(0)" ::: "memory");

    if (t < FDIM) hl[t] = 0.f;
    float c = 0.f;
    float xv0 = xg[t];
    float xv1 = xg[G4H + t];
    __syncthreads();

    for (int step = 0; step < T; ++step) {
        // distributed h: lane holds h[2*lane], h[2*lane+1]
        f32x2 hloc = *(const f32x2*)(hl + 2 * lane);
        float xcur = xv0;
        xv0 = xv1;
        if (step + 2 < T) xv1 = xg[(size_t)(step + 2) * G4H + t];

        f32x2 acc0 = {0.f, 0.f}, acc1 = {0.f, 0.f}, acc2 = {0.f, 0.f}, acc3 = {0.f, 0.f};
        #pragma unroll
        for (int m = 0; m < 16; ++m) {
            int p = s * 16 + m;   // source lane holding h[2p], h[2p+1]
            f32x2 hp;
            hp.x = __int_as_float(__builtin_amdgcn_readlane(__float_as_int(hloc.x), p));
            hp.y = __int_as_float(__builtin_amdgcn_readlane(__float_as_int(hloc.y), p));
            asm volatile("v_pk_fma_f32 %0, %1, %2, %0" : "+v"(acc0) : "v"(w2[0][m]), "s"(hp));
            asm volatile("v_pk_fma_f32 %0, %1, %2, %0" : "+v"(acc1) : "v"(w2[1][m]), "s"(hp));
            asm volatile("v_pk_fma_f32 %0, %1, %2, %0" : "+v"(acc2) : "v"(w2[2][m]), "s"(hp));
            asm volatile("v_pk_fma_f32 %0, %1, %2, %0" : "+v"(acc3) : "v"(w2[3][m]), "s"(hp));
        }
        // horizontal add + fold xg (this thread's xg column t = gate s, index j)
        float4 pw;
        pw.x = acc0.x + acc0.y + (s == 0 ? xcur : 0.f);
        pw.y = acc1.x + acc1.y + (s == 1 ? xcur : 0.f);
        pw.z = acc2.x + acc2.y + (s == 2 ? xcur : 0.f);
        pw.w = acc3.x + acc3.y + (s == 3 ? xcur : 0.f);
        *(float4*)(part + s * 512 + j * 4) = pw;
        __syncthreads();

        // combine partials (replicated across slice groups)
        float4 q0 = *(const float4*)(part + 0 * 512 + j * 4);
        float4 q1 = *(const float4*)(part + 1 * 512 + j * 4);
        float4 q2 = *(const float4*)(part + 2 * 512 + j * 4);
        float4 q3 = *(const float4*)(part + 3 * 512 + j * 4);
        float gi = (q0.x + q1.x) + (q2.x + q3.x);
        float gf = (q0.y + q1.y) + (q2.y + q3.y);
        float gg = (q0.z + q1.z) + (q2.z + q3.z);
        float go = (q0.w + q1.w) + (q2.w + q3.w);
        gi = 1.f / (1.f + __expf(-gi));
        gf = 1.f / (1.f + __expf(-gf));
        gg = 1.f - 2.f / (1.f + __expf(2.f * gg));
        go = 1.f / (1.f + __expf(-go));
        c = gf * c + gi * gg;
        float th = 1.f - 2.f / (1.f + __expf(2.f * c));
        float h = go * th;
        if (s == 0) {
            hl[j] = h;
            hs[(size_t)step * FDIM + j] = h;
        }
        __syncthreads();
    }
}

// ---------------------------------------------------------------------------
// out[M x 12] = hs[M x 128] @ w_fc^T + b_fc
// ---------------------------------------------------------------------------
__global__ __launch_bounds__(256) void fc_kernel(const float* __restrict__ hs,
                                                 const float* __restrict__ wfc,
                                                 const float* __restrict__ bfc,
                                                 float* __restrict__ out, int M) {
    __shared__ float wl[12 * FDIM];
    __shared__ float bl[12];
    const int tid = threadIdx.x;
    for (int i = tid; i < 12 * FDIM / 4; i += 256)
        ((float4*)wl)[i] = ((const float4*)wfc)[i];
    if (tid < 12) bl[tid] = bfc[tid];
    __syncthreads();

    int i = blockIdx.x * 256 + tid;
    if (i >= M) return;
    const float* hrow = hs + (size_t)i * FDIM;
    float acc[12];
    #pragma unroll
    for (int t = 0; t < 12; ++t) acc[t] = bl[t];
    for (int k = 0; k < FDIM; k += 4) {
        float4 h4 = *(const float4*)(hrow + k);
        #pragma unroll
        for (int t = 0; t < 12; ++t) {
            acc[t] += h4.x * wl[t * FDIM + k] + h4.y * wl[t * FDIM + k + 1]
                    + h4.z * wl[t * FDIM + k + 2] + h4.w * wl[t * FDIM + k + 3];
        }
    }
    #pragma unroll
    for (int t = 0; t < 12; ++t) out[(size_t)i * 12 + t] = acc[t];
}

// ---------------------------------------------------------------------------
extern "C" void kernel_launch(void* const* d_in, const int* in_sizes, int n_in,
                              void* d_out, int out_size, void* d_ws, size_t ws_size,
                              hipStream_t stream) {
    const float* x    = (const float*)d_in[0];
    const int*   ei   = (const int*)  d_in[1];
    const float* W1   = (const float*)d_in[2];
    const float* b1   = (const float*)d_in[3];
    const float* W2   = (const float*)d_in[4];
    const float* b2   = (const float*)d_in[5];
    const float* w_ih = (const float*)d_in[6];
    const float* w_hh = (const float*)d_in[7];
    const float* b_ih = (const float*)d_in[8];
    const float* b_hh = (const float*)d_in[9];
    const float* w_fc = (const float*)d_in[10];
    const float* b_fc = (const float*)d_in[11];

    const int N = in_sizes[0] / FDIM;     // 20000
    const int E = in_sizes[1] / 2;        // 1280000

    float* ws   = (float*)d_ws;
    int*   deg  = (int*)ws;               // [0, 20480) ints
    float* dinv = ws + 20480;
    float* hB   = ws + 40960;             // h2: N*128
    float* big  = hB + (size_t)N * FDIM;  // xg region (N*512), aliases y/hA
    float* y    = big;                    // N*128 (dead before xg written)
    float* hA   = big + (size_t)N * FDIM; // h1   (dead before xg written)
    float* xg   = big;                    // N*512
    float* hs   = big + (size_t)N * G4H;  // N*128

    hipMemsetAsync(deg, 0, (size_t)N * sizeof(int), stream);
    deg_kernel<<<(E + 255) / 256, 256, 0, stream>>>(ei, deg, E);
    dinv_kernel<<<(N + 255) / 256, 256, 0, stream>>>(deg, dinv, N);

    const int gblocks = (N + 31) / 32;
    // layer 1
    gemm_nn<<<gblocks, 256, 0, stream>>>(x, W1, y, N);
    agg_init<<<(N * 32 + 255) / 256, 256, 0, stream>>>(y, dinv, b1, hA, N);
    agg_edges<<<(E * 32 + 255) / 256, 256, 0, stream>>>(y, ei, dinv, hA, E);
    relu_kernel<<<(N * 32 + 255) / 256, 256, 0, stream>>>(hA, N * 32);
    // layer 2
    gemm_nn<<<gblocks, 256, 0, stream>>>(hA, W2, y, N);
    agg_init<<<(N * 32 + 255) / 256, 256, 0, stream>>>(y, dinv, b2, hB, N);
    agg_edges<<<(E * 32 + 255) / 256, 256, 0, stream>>>(y, ei, dinv, hB, E);
    relu_kernel<<<(N * 32 + 255) / 256, 256, 0, stream>>>(hB, N * 32);
    // LSTM input projection
    gemm_nt_xg<<<dim3(gblocks, 4), 256, 0, stream>>>(hB, w_ih, b_ih, b_hh, xg, N);
    // sequential LSTM (single CU — the critical path)
    lstm_kernel<<<1, 512, 0, stream>>>(xg, w_hh, hs, N);
    // final projection
    fc_kernel<<<(N + 255) / 256, 256, 0, stream>>>(hs, w_fc, b_fc, (float*)d_out, N);
}

// Round 4
// 23834.549 us; speedup vs baseline: 1.0561x; 1.0268x over previous
//
#include <hip/hip_runtime.h>
#include <hip/hip_bf16.h>

// Problem constants (fixed by the reference)
#define FDIM 128      // F_IN == H == 128
#define G4H  512      // 4*H

typedef float f32x2 __attribute__((ext_vector_type(2)));

// ---------------------------------------------------------------------------
// degree / normalization
// ---------------------------------------------------------------------------
__global__ void deg_kernel(const int* __restrict__ ei, int* __restrict__ deg, int E) {
    int e = blockIdx.x * 256 + threadIdx.x;
    if (e < E) atomicAdd(&deg[ei[E + e]], 1);
}

__global__ void dinv_kernel(const int* __restrict__ deg, float* __restrict__ dinv, int N) {
    int n = blockIdx.x * 256 + threadIdx.x;
    if (n < N) dinv[n] = rsqrtf((float)(deg[n] + 1));   // +1 self-loop
}

// ---------------------------------------------------------------------------
// C[M x 128] = A[M x 128] @ B[128 x 128]   (B is K-major: B[k*128 + j])
// ---------------------------------------------------------------------------
__global__ __launch_bounds__(256) void gemm_nn(const float* __restrict__ A,
                                               const float* __restrict__ B,
                                               float* __restrict__ C, int M) {
    __shared__ float Bl[64 * 132];
    __shared__ float Al[32][FDIM];
    const int tid = threadIdx.x;
    const int row0 = blockIdx.x * 32;

    for (int i = tid * 4; i < 32 * FDIM; i += 1024) {
        int r = i >> 7, k = i & 127;
        int row = row0 + r;
        float4 v = make_float4(0.f, 0.f, 0.f, 0.f);
        if (row < M) v = *(const float4*)(A + (size_t)row * FDIM + k);
        *(float4*)&Al[r][k] = v;
    }

    const int jg = tid & 31, rg = tid >> 5;
    float acc[4][4] = {};

    for (int kh = 0; kh < 2; ++kh) {
        __syncthreads();
        for (int i = tid * 4; i < 64 * FDIM; i += 1024) {
            int k = i >> 7, j = i & 127;
            *(float4*)&Bl[k * 132 + j] = *(const float4*)(B + (size_t)(kh * 64 + k) * FDIM + j);
        }
        __syncthreads();
        #pragma unroll 4
        for (int k = 0; k < 64; ++k) {
            float4 b4 = *(const float4*)&Bl[k * 132 + jg * 4];
            #pragma unroll
            for (int rr = 0; rr < 4; ++rr) {
                float a = Al[rg * 4 + rr][kh * 64 + k];
                acc[rr][0] += a * b4.x; acc[rr][1] += a * b4.y;
                acc[rr][2] += a * b4.z; acc[rr][3] += a * b4.w;
            }
        }
    }
    #pragma unroll
    for (int rr = 0; rr < 4; ++rr) {
        int row = row0 + rg * 4 + rr;
        if (row < M) {
            float4 v = make_float4(acc[rr][0], acc[rr][1], acc[rr][2], acc[rr][3]);
            *(float4*)(C + (size_t)row * FDIM + jg * 4) = v;
        }
    }
}

// ---------------------------------------------------------------------------
// xg[M x 512] = A[M x 128] @ B^T  (+ b_ih + b_hh), B is [512 x 128] row-major.
// ---------------------------------------------------------------------------
__global__ __launch_bounds__(256) void gemm_nt_xg(const float* __restrict__ A,
                                                  const float* __restrict__ B,
                                                  const float* __restrict__ bih,
                                                  const float* __restrict__ bhh,
                                                  float* __restrict__ C, int M) {
    __shared__ float Bl[64 * 132];
    __shared__ float Al[32][FDIM];
    const int tid = threadIdx.x;
    const int row0 = blockIdx.x * 32;
    const int chunk = blockIdx.y;

    for (int i = tid * 4; i < 32 * FDIM; i += 1024) {
        int r = i >> 7, k = i & 127;
        int row = row0 + r;
        float4 v = make_float4(0.f, 0.f, 0.f, 0.f);
        if (row < M) v = *(const float4*)(A + (size_t)row * FDIM + k);
        *(float4*)&Al[r][k] = v;
    }

    const int jg = tid & 31, rg = tid >> 5;
    float acc[4][4] = {};

    for (int kh = 0; kh < 2; ++kh) {
        __syncthreads();
        for (int i = tid * 4; i < 128 * 64; i += 1024) {
            int g = i >> 6, kl = i & 63;
            float4 v = *(const float4*)(B + (size_t)(chunk * 128 + g) * FDIM + kh * 64 + kl);
            Bl[(kl + 0) * 132 + g] = v.x;
            Bl[(kl + 1) * 132 + g] = v.y;
            Bl[(kl + 2) * 132 + g] = v.z;
            Bl[(kl + 3) * 132 + g] = v.w;
        }
        __syncthreads();
        #pragma unroll 4
        for (int k = 0; k < 64; ++k) {
            float4 b4 = *(const float4*)&Bl[k * 132 + jg * 4];
            #pragma unroll
            for (int rr = 0; rr < 4; ++rr) {
                float a = Al[rg * 4 + rr][kh * 64 + k];
                acc[rr][0] += a * b4.x; acc[rr][1] += a * b4.y;
                acc[rr][2] += a * b4.z; acc[rr][3] += a * b4.w;
            }
        }
    }
    const int col0 = chunk * 128 + jg * 4;
    float4 bsum = make_float4(bih[col0 + 0] + bhh[col0 + 0],
                              bih[col0 + 1] + bhh[col0 + 1],
                              bih[col0 + 2] + bhh[col0 + 2],
                              bih[col0 + 3] + bhh[col0 + 3]);
    #pragma unroll
    for (int rr = 0; rr < 4; ++rr) {
        int row = row0 + rg * 4 + rr;
        if (row < M) {
            float4 v = make_float4(acc[rr][0] + bsum.x, acc[rr][1] + bsum.y,
                                   acc[rr][2] + bsum.z, acc[rr][3] + bsum.w);
            *(float4*)(C + (size_t)row * G4H + col0) = v;
        }
    }
}

// ---------------------------------------------------------------------------
// GCN aggregation
// ---------------------------------------------------------------------------
__global__ void agg_init(const float* __restrict__ y, const float* __restrict__ dinv,
                         const float* __restrict__ bias, float* __restrict__ o, int N) {
    int idx = blockIdx.x * 256 + threadIdx.x;
    int n = idx >> 5, cc = (idx & 31) * 4;
    if (n >= N) return;
    float s = dinv[n]; s = s * s;
    float4 v = *(const float4*)(y + (size_t)n * FDIM + cc);
    float4 b = *(const float4*)(bias + cc);
    float4 r = make_float4(v.x * s + b.x, v.y * s + b.y, v.z * s + b.z, v.w * s + b.w);
    *(float4*)(o + (size_t)n * FDIM + cc) = r;
}

__global__ void agg_edges(const float* __restrict__ y, const int* __restrict__ ei,
                          const float* __restrict__ dinv, float* __restrict__ o, int E) {
    int idx = blockIdx.x * 256 + threadIdx.x;
    int e = idx >> 5, cc = (idx & 31) * 4;
    if (e >= E) return;
    int s = ei[e], d = ei[E + e];
    float nrm = dinv[s] * dinv[d];
    float4 v = *(const float4*)(y + (size_t)s * FDIM + cc);
    float* dst = o + (size_t)d * FDIM + cc;
    atomicAdd(dst + 0, v.x * nrm);
    atomicAdd(dst + 1, v.y * nrm);
    atomicAdd(dst + 2, v.z * nrm);
    atomicAdd(dst + 3, v.w * nrm);
}

__global__ void relu_kernel(float* __restrict__ x, int n4) {
    int i = blockIdx.x * 256 + threadIdx.x;
    if (i < n4) {
        float4 v = ((float4*)x)[i];
        v.x = fmaxf(v.x, 0.f); v.y = fmaxf(v.y, 0.f);
        v.z = fmaxf(v.z, 0.f); v.w = fmaxf(v.w, 0.f);
        ((float4*)x)[i] = v;
    }
}

// ---------------------------------------------------------------------------
// LSTM v4: 1024 threads (16 waves). Thread (w=t>>7, j=t&127) computes the 4
// gate rows of hidden index j over K-slice [16w,16w+16): 32 f32x2 = 64 weight
// VGPRs (the allocator refused 128/thread at 512 threads in v2/v3 — spilled
// to scratch, 256 KB/step reload = the 20 ms plateau). h is read via
// wave-uniform LDS float4 broadcast (conflict-free, LDS pipe) — no readlanes.
// Partials in padded LDS part[j][36]; phase B = 2 waves, thread j sums 8
// slices x 4 gates (8x b128, full-BW pattern), folds prefetched xg, does the
// activations, owns c_j in a register, writes h to LDS + hs. 2 barriers/step.
// ---------------------------------------------------------------------------
__global__ void __launch_bounds__(1024, 4)
__attribute__((amdgpu_waves_per_eu(4, 4)))
lstm_kernel(const float* __restrict__ xg, const float* __restrict__ whh,
            float* __restrict__ hs, int T) {
    __shared__ float hl[FDIM];
    __shared__ float part[128 * 36];   // [j][w*4+g], row stride 36 floats (144 B, 16B-aligned)
    const int t = threadIdx.x;
    const int j = t & 127;
    const int w = t >> 7;              // slice id 0..7, wave-uniform

    // Pinned weight load: 4 gates x K-slice of 16 -> 32 f32x2 = 64 VGPRs.
    f32x2 w2[4][8];
    #pragma unroll
    for (int g = 0; g < 4; ++g) {
        const float* wr = whh + (size_t)(g * FDIM + j) * FDIM + 16 * w;
        #pragma unroll
        for (int m = 0; m < 8; ++m)
            asm volatile("global_load_dwordx2 %0, %1, off"
                         : "=v"(w2[g][m]) : "v"(wr + 2 * m));
    }
    asm volatile("s_waitcnt vmcnt(0)" ::: "memory");

    float c = 0.f;
    float xv0[4], xv1[4];
    if (t < FDIM) {
        hl[t] = 0.f;
        #pragma unroll
        for (int g = 0; g < 4; ++g) {
            xv0[g] = xg[g * FDIM + t];
            xv1[g] = xg[G4H + g * FDIM + t];
        }
    }
    __syncthreads();

    for (int step = 0; step < T; ++step) {
        // ---- phase A: partial GEMV, all 16 waves ----
        const float* hb = hl + 16 * w;               // wave-uniform -> broadcast reads
        float4 h0 = *(const float4*)(hb + 0);
        float4 h1 = *(const float4*)(hb + 4);
        float4 h2 = *(const float4*)(hb + 8);
        float4 h3 = *(const float4*)(hb + 12);
        f32x2 hbc[8];
        hbc[0] = f32x2{h0.x, h0.y}; hbc[1] = f32x2{h0.z, h0.w};
        hbc[2] = f32x2{h1.x, h1.y}; hbc[3] = f32x2{h1.z, h1.w};
        hbc[4] = f32x2{h2.x, h2.y}; hbc[5] = f32x2{h2.z, h2.w};
        hbc[6] = f32x2{h3.x, h3.y}; hbc[7] = f32x2{h3.z, h3.w};

        f32x2 a0 = {0.f, 0.f}, a1 = {0.f, 0.f}, a2 = {0.f, 0.f}, a3 = {0.f, 0.f};
        #pragma unroll
        for (int m = 0; m < 8; ++m) {
            asm("v_pk_fma_f32 %0, %1, %2, %0" : "+v"(a0) : "v"(w2[0][m]), "v"(hbc[m]));
            asm("v_pk_fma_f32 %0, %1, %2, %0" : "+v"(a1) : "v"(w2[1][m]), "v"(hbc[m]));
            asm("v_pk_fma_f32 %0, %1, %2, %0" : "+v"(a2) : "v"(w2[2][m]), "v"(hbc[m]));
            asm("v_pk_fma_f32 %0, %1, %2, %0" : "+v"(a3) : "v"(w2[3][m]), "v"(hbc[m]));
        }
        float4 pw = make_float4(a0.x + a0.y, a1.x + a1.y, a2.x + a2.y, a3.x + a3.y);
        *(float4*)(part + j * 36 + w * 4) = pw;
        __syncthreads();

        // ---- phase B: 2 waves, thread j does combine + activations + state ----
        if (t < FDIM) {
            const float* pr = part + t * 36;
            float4 s0 = *(const float4*)(pr + 0);
            float4 s1 = *(const float4*)(pr + 4);
            float4 s2 = *(const float4*)(pr + 8);
            float4 s3 = *(const float4*)(pr + 12);
            float4 s4 = *(const float4*)(pr + 16);
            float4 s5 = *(const float4*)(pr + 20);
            float4 s6 = *(const float4*)(pr + 24);
            float4 s7 = *(const float4*)(pr + 28);
            float gi = ((s0.x + s1.x) + (s2.x + s3.x)) + ((s4.x + s5.x) + (s6.x + s7.x)) + xv0[0];
            float gf = ((s0.y + s1.y) + (s2.y + s3.y)) + ((s4.y + s5.y) + (s6.y + s7.y)) + xv0[1];
            float gg = ((s0.z + s1.z) + (s2.z + s3.z)) + ((s4.z + s5.z) + (s6.z + s7.z)) + xv0[2];
            float go = ((s0.w + s1.w) + (s2.w + s3.w)) + ((s4.w + s5.w) + (s6.w + s7.w)) + xv0[3];
            // rotate xg prefetch (2-deep)
            #pragma unroll
            for (int g = 0; g < 4; ++g) xv0[g] = xv1[g];
            if (step + 2 < T) {
                #pragma unroll
                for (int g = 0; g < 4; ++g)
                    xv1[g] = xg[(size_t)(step + 2) * G4H + g * FDIM + t];
            }
            gi = 1.f / (1.f + __expf(-gi));
            gf = 1.f / (1.f + __expf(-gf));
            gg = 1.f - 2.f / (1.f + __expf(2.f * gg));
            go = 1.f / (1.f + __expf(-go));
            c = gf * c + gi * gg;
            float th = 1.f - 2.f / (1.f + __expf(2.f * c));
            float h = go * th;
            hl[t] = h;
            hs[(size_t)step * FDIM + t] = h;
        }
        __syncthreads();
    }
}

// ---------------------------------------------------------------------------
// out[M x 12] = hs[M x 128] @ w_fc^T + b_fc
// ---------------------------------------------------------------------------
__global__ __launch_bounds__(256) void fc_kernel(const float* __restrict__ hs,
                                                 const float* __restrict__ wfc,
                                                 const float* __restrict__ bfc,
                                                 float* __restrict__ out, int M) {
    __shared__ float wl[12 * FDIM];
    __shared__ float bl[12];
    const int tid = threadIdx.x;
    for (int i = tid; i < 12 * FDIM / 4; i += 256)
        ((float4*)wl)[i] = ((const float4*)wfc)[i];
    if (tid < 12) bl[tid] = bfc[tid];
    __syncthreads();

    int i = blockIdx.x * 256 + tid;
    if (i >= M) return;
    const float* hrow = hs + (size_t)i * FDIM;
    float acc[12];
    #pragma unroll
    for (int t = 0; t < 12; ++t) acc[t] = bl[t];
    for (int k = 0; k < FDIM; k += 4) {
        float4 h4 = *(const float4*)(hrow + k);
        #pragma unroll
        for (int t = 0; t < 12; ++t) {
            acc[t] += h4.x * wl[t * FDIM + k] + h4.y * wl[t * FDIM + k + 1]
                    + h4.z * wl[t * FDIM + k + 2] + h4.w * wl[t * FDIM + k + 3];
        }
    }
    #pragma unroll
    for (int t = 0; t < 12; ++t) out[(size_t)i * 12 + t] = acc[t];
}

// ---------------------------------------------------------------------------
extern "C" void kernel_launch(void* const* d_in, const int* in_sizes, int n_in,
                              void* d_out, int out_size, void* d_ws, size_t ws_size,
                              hipStream_t stream) {
    const float* x    = (const float*)d_in[0];
    const int*   ei   = (const int*)  d_in[1];
    const float* W1   = (const float*)d_in[2];
    const float* b1   = (const float*)d_in[3];
    const float* W2   = (const float*)d_in[4];
    const float* b2   = (const float*)d_in[5];
    const float* w_ih = (const float*)d_in[6];
    const float* w_hh = (const float*)d_in[7];
    const float* b_ih = (const float*)d_in[8];
    const float* b_hh = (const float*)d_in[9];
    const float* w_fc = (const float*)d_in[10];
    const float* b_fc = (const float*)d_in[11];

    const int N = in_sizes[0] / FDIM;     // 20000
    const int E = in_sizes[1] / 2;        // 1280000

    float* ws   = (float*)d_ws;
    int*   deg  = (int*)ws;               // [0, 20480) ints
    float* dinv = ws + 20480;
    float* hB   = ws + 40960;             // h2: N*128
    float* big  = hB + (size_t)N * FDIM;  // xg region (N*512), aliases y/hA
    float* y    = big;                    // N*128 (dead before xg written)
    float* hA   = big + (size_t)N * FDIM; // h1   (dead before xg written)
    float* xg   = big;                    // N*512
    float* hs   = big + (size_t)N * G4H;  // N*128

    hipMemsetAsync(deg, 0, (size_t)N * sizeof(int), stream);
    deg_kernel<<<(E + 255) / 256, 256, 0, stream>>>(ei, deg, E);
    dinv_kernel<<<(N + 255) / 256, 256, 0, stream>>>(deg, dinv, N);

    const int gblocks = (N + 31) / 32;
    // layer 1
    gemm_nn<<<gblocks, 256, 0, stream>>>(x, W1, y, N);
    agg_init<<<(N * 32 + 255) / 256, 256, 0, stream>>>(y, dinv, b1, hA, N);
    agg_edges<<<(E * 32 + 255) / 256, 256, 0, stream>>>(y, ei, dinv, hA, E);
    relu_kernel<<<(N * 32 + 255) / 256, 256, 0, stream>>>(hA, N * 32);
    // layer 2
    gemm_nn<<<gblocks, 256, 0, stream>>>(hA, W2, y, N);
    agg_init<<<(N * 32 + 255) / 256, 256, 0, stream>>>(y, dinv, b2, hB, N);
    agg_edges<<<(E * 32 + 255) / 256, 256, 0, stream>>>(y, ei, dinv, hB, E);
    relu_kernel<<<(N * 32 + 255) / 256, 256, 0, stream>>>(hB, N * 32);
    // LSTM input projection
    gemm_nt_xg<<<dim3(gblocks, 4), 256, 0, stream>>>(hB, w_ih, b_ih, b_hh, xg, N);
    // sequential LSTM (single CU — the critical path)
    lstm_kernel<<<1, 1024, 0, stream>>>(xg, w_hh, hs, N);
    // final projection
    fc_kernel<<<(N + 255) / 256, 256, 0, stream>>>(hs, w_fc, b_fc, (float*)d_out, N);
}

// Round 5
// 22017.757 us; speedup vs baseline: 1.1433x; 1.0825x over previous
//
#include <hip/hip_runtime.h>
#include <hip/hip_bf16.h>
#include <hip/hip_fp16.h>

// Problem constants (fixed by the reference)
#define FDIM 128      // F_IN == H == 128
#define G4H  512      // 4*H

typedef float f32x2 __attribute__((ext_vector_type(2)));

// ---------------------------------------------------------------------------
// degree / normalization
// ---------------------------------------------------------------------------
__global__ void deg_kernel(const int* __restrict__ ei, int* __restrict__ deg, int E) {
    int e = blockIdx.x * 256 + threadIdx.x;
    if (e < E) atomicAdd(&deg[ei[E + e]], 1);
}

__global__ void dinv_kernel(const int* __restrict__ deg, float* __restrict__ dinv, int N) {
    int n = blockIdx.x * 256 + threadIdx.x;
    if (n < N) dinv[n] = rsqrtf((float)(deg[n] + 1));   // +1 self-loop
}

// ---------------------------------------------------------------------------
// Pack w_hh [512 x 128] fp32 -> [512 x 64] packed half2 (K-pairs).
// ---------------------------------------------------------------------------
__global__ void pack_whh(const float* __restrict__ whh, float* __restrict__ whp, int n) {
    int i = blockIdx.x * 256 + threadIdx.x;   // n = 512*64
    if (i >= n) return;
    int row = i >> 6, p = i & 63;
    __half lo = __float2half(whh[row * FDIM + 2 * p]);
    __half hi = __float2half(whh[row * FDIM + 2 * p + 1]);
    unsigned u = ((unsigned)__half_as_ushort(hi) << 16) | (unsigned)__half_as_ushort(lo);
    whp[i] = __uint_as_float(u);
}

// ---------------------------------------------------------------------------
// C[M x 128] = A[M x 128] @ B[128 x 128]   (B is K-major: B[k*128 + j])
// ---------------------------------------------------------------------------
__global__ __launch_bounds__(256) void gemm_nn(const float* __restrict__ A,
                                               const float* __restrict__ B,
                                               float* __restrict__ C, int M) {
    __shared__ float Bl[64 * 132];
    __shared__ float Al[32][FDIM];
    const int tid = threadIdx.x;
    const int row0 = blockIdx.x * 32;

    for (int i = tid * 4; i < 32 * FDIM; i += 1024) {
        int r = i >> 7, k = i & 127;
        int row = row0 + r;
        float4 v = make_float4(0.f, 0.f, 0.f, 0.f);
        if (row < M) v = *(const float4*)(A + (size_t)row * FDIM + k);
        *(float4*)&Al[r][k] = v;
    }

    const int jg = tid & 31, rg = tid >> 5;
    float acc[4][4] = {};

    for (int kh = 0; kh < 2; ++kh) {
        __syncthreads();
        for (int i = tid * 4; i < 64 * FDIM; i += 1024) {
            int k = i >> 7, j = i & 127;
            *(float4*)&Bl[k * 132 + j] = *(const float4*)(B + (size_t)(kh * 64 + k) * FDIM + j);
        }
        __syncthreads();
        #pragma unroll 4
        for (int k = 0; k < 64; ++k) {
            float4 b4 = *(const float4*)&Bl[k * 132 + jg * 4];
            #pragma unroll
            for (int rr = 0; rr < 4; ++rr) {
                float a = Al[rg * 4 + rr][kh * 64 + k];
                acc[rr][0] += a * b4.x; acc[rr][1] += a * b4.y;
                acc[rr][2] += a * b4.z; acc[rr][3] += a * b4.w;
            }
        }
    }
    #pragma unroll
    for (int rr = 0; rr < 4; ++rr) {
        int row = row0 + rg * 4 + rr;
        if (row < M) {
            float4 v = make_float4(acc[rr][0], acc[rr][1], acc[rr][2], acc[rr][3]);
            *(float4*)(C + (size_t)row * FDIM + jg * 4) = v;
        }
    }
}

// ---------------------------------------------------------------------------
// xg[M x 512] = A[M x 128] @ B^T  (+ b_ih + b_hh), B is [512 x 128] row-major.
// ---------------------------------------------------------------------------
__global__ __launch_bounds__(256) void gemm_nt_xg(const float* __restrict__ A,
                                                  const float* __restrict__ B,
                                                  const float* __restrict__ bih,
                                                  const float* __restrict__ bhh,
                                                  float* __restrict__ C, int M) {
    __shared__ float Bl[64 * 132];
    __shared__ float Al[32][FDIM];
    const int tid = threadIdx.x;
    const int row0 = blockIdx.x * 32;
    const int chunk = blockIdx.y;

    for (int i = tid * 4; i < 32 * FDIM; i += 1024) {
        int r = i >> 7, k = i & 127;
        int row = row0 + r;
        float4 v = make_float4(0.f, 0.f, 0.f, 0.f);
        if (row < M) v = *(const float4*)(A + (size_t)row * FDIM + k);
        *(float4*)&Al[r][k] = v;
    }

    const int jg = tid & 31, rg = tid >> 5;
    float acc[4][4] = {};

    for (int kh = 0; kh < 2; ++kh) {
        __syncthreads();
        for (int i = tid * 4; i < 128 * 64; i += 1024) {
            int g = i >> 6, kl = i & 63;
            float4 v = *(const float4*)(B + (size_t)(chunk * 128 + g) * FDIM + kh * 64 + kl);
            Bl[(kl + 0) * 132 + g] = v.x;
            Bl[(kl + 1) * 132 + g] = v.y;
            Bl[(kl + 2) * 132 + g] = v.z;
            Bl[(kl + 3) * 132 + g] = v.w;
        }
        __syncthreads();
        #pragma unroll 4
        for (int k = 0; k < 64; ++k) {
            float4 b4 = *(const float4*)&Bl[k * 132 + jg * 4];
            #pragma unroll
            for (int rr = 0; rr < 4; ++rr) {
                float a = Al[rg * 4 + rr][kh * 64 + k];
                acc[rr][0] += a * b4.x; acc[rr][1] += a * b4.y;
                acc[rr][2] += a * b4.z; acc[rr][3] += a * b4.w;
            }
        }
    }
    const int col0 = chunk * 128 + jg * 4;
    float4 bsum = make_float4(bih[col0 + 0] + bhh[col0 + 0],
                              bih[col0 + 1] + bhh[col0 + 1],
                              bih[col0 + 2] + bhh[col0 + 2],
                              bih[col0 + 3] + bhh[col0 + 3]);
    #pragma unroll
    for (int rr = 0; rr < 4; ++rr) {
        int row = row0 + rg * 4 + rr;
        if (row < M) {
            float4 v = make_float4(acc[rr][0] + bsum.x, acc[rr][1] + bsum.y,
                                   acc[rr][2] + bsum.z, acc[rr][3] + bsum.w);
            *(float4*)(C + (size_t)row * G4H + col0) = v;
        }
    }
}

// ---------------------------------------------------------------------------
// GCN aggregation
// ---------------------------------------------------------------------------
__global__ void agg_init(const float* __restrict__ y, const float* __restrict__ dinv,
                         const float* __restrict__ bias, float* __restrict__ o, int N) {
    int idx = blockIdx.x * 256 + threadIdx.x;
    int n = idx >> 5, cc = (idx & 31) * 4;
    if (n >= N) return;
    float s = dinv[n]; s = s * s;
    float4 v = *(const float4*)(y + (size_t)n * FDIM + cc);
    float4 b = *(const float4*)(bias + cc);
    float4 r = make_float4(v.x * s + b.x, v.y * s + b.y, v.z * s + b.z, v.w * s + b.w);
    *(float4*)(o + (size_t)n * FDIM + cc) = r;
}

__global__ void agg_edges(const float* __restrict__ y, const int* __restrict__ ei,
                          const float* __restrict__ dinv, float* __restrict__ o, int E) {
    int idx = blockIdx.x * 256 + threadIdx.x;
    int e = idx >> 5, cc = (idx & 31) * 4;
    if (e >= E) return;
    int s = ei[e], d = ei[E + e];
    float nrm = dinv[s] * dinv[d];
    float4 v = *(const float4*)(y + (size_t)s * FDIM + cc);
    float* dst = o + (size_t)d * FDIM + cc;
    atomicAdd(dst + 0, v.x * nrm);
    atomicAdd(dst + 1, v.y * nrm);
    atomicAdd(dst + 2, v.z * nrm);
    atomicAdd(dst + 3, v.w * nrm);
}

__global__ void relu_kernel(float* __restrict__ x, int n4) {
    int i = blockIdx.x * 256 + threadIdx.x;
    if (i < n4) {
        float4 v = ((float4*)x)[i];
        v.x = fmaxf(v.x, 0.f); v.y = fmaxf(v.y, 0.f);
        v.z = fmaxf(v.z, 0.f); v.w = fmaxf(v.w, 0.f);
        ((float4*)x)[i] = v;
    }
}

// ---------------------------------------------------------------------------
// LSTM v5: fp16 weights, fp32 accumulate (v_dot2_f32_f16).
// 1024 threads, thread (w=t>>7, j=t&127) does 4 gate rows of hidden index j
// over K-slice [16w,16w+16): 32 PACKED half2 VGPRs — fits the ~60-VGPR budget
// the allocator has repeatedly chosen (v2-v4 spilled at 64+ fp32 regs/thread).
// h is fp16 in LDS (2 broadcast b128 reads/thread/step). Partials in
// part[w][j*4] (lane-contiguous b128, conflict-free). Phase B: 2 waves,
// thread j sums 8 slices, activations in fp32, owns c_j, writes fp32 hs and
// fp16 h. 2 barriers/step.
// ---------------------------------------------------------------------------
__global__ void __launch_bounds__(1024)
lstm_kernel(const float* __restrict__ xg, const float* __restrict__ whp,
            float* __restrict__ hs, int T) {
    __shared__ __align__(16) __half hl[FDIM];   // fp16 hidden state
    __shared__ float part[8][520];              // [slice][j*4+gate]
    const int t = threadIdx.x;
    const int j = t & 127;
    const int w = t >> 7;                       // slice id 0..7, wave-uniform

    // Weights: 32 packed half2 (as float bit-patterns) = 32 VGPRs.
    // asm volatile scalar dword loads: no tuple-alignment fragmentation,
    // cannot be sunk into the loop.
    float wreg[4][8];
    {
        const float* base = whp + j * 64 + w * 8;    // whp row = g*128+j, 64 half2/row
        #pragma unroll
        for (int g = 0; g < 4; ++g) {
            const float* p = base + g * (FDIM * 64);
            #pragma unroll
            for (int m = 0; m < 8; ++m)
                asm volatile("global_load_dword %0, %1, off"
                             : "=v"(wreg[g][m]) : "v"(p + m));
        }
    }
    asm volatile("s_waitcnt vmcnt(0)" ::: "memory");

    float c = 0.f;
    float xv0[4], xv1[4];
    if (t < FDIM) {
        hl[t] = __float2half(0.f);
        #pragma unroll
        for (int g = 0; g < 4; ++g) {
            xv0[g] = xg[g * FDIM + t];
            xv1[g] = xg[G4H + g * FDIM + t];
        }
    }
    __syncthreads();

    for (int step = 0; step < T; ++step) {
        // ---- phase A: partial GEMV via v_dot2_f32_f16, all 16 waves ----
        const float* hb = (const float*)hl + w * 8;  // 16 halves = 8 float slots, 32B
        float acc0 = 0.f, acc1 = 0.f, acc2 = 0.f, acc3 = 0.f;
        #pragma unroll
        for (int half4 = 0; half4 < 2; ++half4) {
            float4 hq = *(const float4*)(hb + half4 * 4);   // wave-uniform broadcast
            float hf[4] = {hq.x, hq.y, hq.z, hq.w};
            #pragma unroll
            for (int m = 0; m < 4; ++m) {
                int mm = half4 * 4 + m;
                asm("v_dot2_f32_f16 %0, %1, %2, %0" : "+v"(acc0) : "v"(wreg[0][mm]), "v"(hf[m]));
                asm("v_dot2_f32_f16 %0, %1, %2, %0" : "+v"(acc1) : "v"(wreg[1][mm]), "v"(hf[m]));
                asm("v_dot2_f32_f16 %0, %1, %2, %0" : "+v"(acc2) : "v"(wreg[2][mm]), "v"(hf[m]));
                asm("v_dot2_f32_f16 %0, %1, %2, %0" : "+v"(acc3) : "v"(wreg[3][mm]), "v"(hf[m]));
            }
        }
        *(float4*)&part[w][j * 4] = make_float4(acc0, acc1, acc2, acc3);
        __syncthreads();

        // ---- phase B: 2 waves, thread j: combine + activations + state ----
        if (t < FDIM) {
            float4 s0 = *(const float4*)&part[0][t * 4];
            float4 s1 = *(const float4*)&part[1][t * 4];
            float4 a01 = make_float4(s0.x + s1.x, s0.y + s1.y, s0.z + s1.z, s0.w + s1.w);
            float4 s2 = *(const float4*)&part[2][t * 4];
            float4 s3 = *(const float4*)&part[3][t * 4];
            float4 a23 = make_float4(s2.x + s3.x, s2.y + s3.y, s2.z + s3.z, s2.w + s3.w);
            float4 s4 = *(const float4*)&part[4][t * 4];
            float4 s5 = *(const float4*)&part[5][t * 4];
            float4 a45 = make_float4(s4.x + s5.x, s4.y + s5.y, s4.z + s5.z, s4.w + s5.w);
            float4 s6 = *(const float4*)&part[6][t * 4];
            float4 s7 = *(const float4*)&part[7][t * 4];
            float4 a67 = make_float4(s6.x + s7.x, s6.y + s7.y, s6.z + s7.z, s6.w + s7.w);
            float gi = (a01.x + a23.x) + (a45.x + a67.x) + xv0[0];
            float gf = (a01.y + a23.y) + (a45.y + a67.y) + xv0[1];
            float gg = (a01.z + a23.z) + (a45.z + a67.z) + xv0[2];
            float go = (a01.w + a23.w) + (a45.w + a67.w) + xv0[3];
            // rotate xg prefetch (2-deep)
            #pragma unroll
            for (int g = 0; g < 4; ++g) xv0[g] = xv1[g];
            if (step + 2 < T) {
                #pragma unroll
                for (int g = 0; g < 4; ++g)
                    xv1[g] = xg[(size_t)(step + 2) * G4H + g * FDIM + t];
            }
            gi = 1.f / (1.f + __expf(-gi));
            gf = 1.f / (1.f + __expf(-gf));
            gg = 1.f - 2.f / (1.f + __expf(2.f * gg));
            go = 1.f / (1.f + __expf(-go));
            c = gf * c + gi * gg;
            float th = 1.f - 2.f / (1.f + __expf(2.f * c));
            float h = go * th;
            hs[(size_t)step * FDIM + t] = h;
            hl[t] = __float2half(h);
        }
        __syncthreads();
    }
}

// ---------------------------------------------------------------------------
// out[M x 12] = hs[M x 128] @ w_fc^T + b_fc
// ---------------------------------------------------------------------------
__global__ __launch_bounds__(256) void fc_kernel(const float* __restrict__ hs,
                                                 const float* __restrict__ wfc,
                                                 const float* __restrict__ bfc,
                                                 float* __restrict__ out, int M) {
    __shared__ float wl[12 * FDIM];
    __shared__ float bl[12];
    const int tid = threadIdx.x;
    for (int i = tid; i < 12 * FDIM / 4; i += 256)
        ((float4*)wl)[i] = ((const float4*)wfc)[i];
    if (tid < 12) bl[tid] = bfc[tid];
    __syncthreads();

    int i = blockIdx.x * 256 + tid;
    if (i >= M) return;
    const float* hrow = hs + (size_t)i * FDIM;
    float acc[12];
    #pragma unroll
    for (int t = 0; t < 12; ++t) acc[t] = bl[t];
    for (int k = 0; k < FDIM; k += 4) {
        float4 h4 = *(const float4*)(hrow + k);
        #pragma unroll
        for (int t = 0; t < 12; ++t) {
            acc[t] += h4.x * wl[t * FDIM + k] + h4.y * wl[t * FDIM + k + 1]
                    + h4.z * wl[t * FDIM + k + 2] + h4.w * wl[t * FDIM + k + 3];
        }
    }
    #pragma unroll
    for (int t = 0; t < 12; ++t) out[(size_t)i * 12 + t] = acc[t];
}

// ---------------------------------------------------------------------------
extern "C" void kernel_launch(void* const* d_in, const int* in_sizes, int n_in,
                              void* d_out, int out_size, void* d_ws, size_t ws_size,
                              hipStream_t stream) {
    const float* x    = (const float*)d_in[0];
    const int*   ei   = (const int*)  d_in[1];
    const float* W1   = (const float*)d_in[2];
    const float* b1   = (const float*)d_in[3];
    const float* W2   = (const float*)d_in[4];
    const float* b2   = (const float*)d_in[5];
    const float* w_ih = (const float*)d_in[6];
    const float* w_hh = (const float*)d_in[7];
    const float* b_ih = (const float*)d_in[8];
    const float* b_hh = (const float*)d_in[9];
    const float* w_fc = (const float*)d_in[10];
    const float* b_fc = (const float*)d_in[11];

    const int N = in_sizes[0] / FDIM;     // 20000
    const int E = in_sizes[1] / 2;        // 1280000

    float* ws   = (float*)d_ws;
    int*   deg  = (int*)ws;               // [0, 20480) ints
    float* dinv = ws + 20480;
    float* whp  = ws + 40960;             // packed fp16 w_hh: 512*64 slots
    float* hB   = ws + 40960 + 32768;     // h2: N*128
    float* big  = hB + (size_t)N * FDIM;  // xg region (N*512), aliases y/hA
    float* y    = big;                    // N*128 (dead before xg written)
    float* hA   = big + (size_t)N * FDIM; // h1   (dead before xg written)
    float* xg   = big;                    // N*512
    float* hs   = big + (size_t)N * G4H;  // N*128

    hipMemsetAsync(deg, 0, (size_t)N * sizeof(int), stream);
    deg_kernel<<<(E + 255) / 256, 256, 0, stream>>>(ei, deg, E);
    dinv_kernel<<<(N + 255) / 256, 256, 0, stream>>>(deg, dinv, N);
    pack_whh<<<(512 * 64 + 255) / 256, 256, 0, stream>>>(w_hh, whp, 512 * 64);

    const int gblocks = (N + 31) / 32;
    // layer 1
    gemm_nn<<<gblocks, 256, 0, stream>>>(x, W1, y, N);
    agg_init<<<(N * 32 + 255) / 256, 256, 0, stream>>>(y, dinv, b1, hA, N);
    agg_edges<<<(E * 32 + 255) / 256, 256, 0, stream>>>(y, ei, dinv, hA, E);
    relu_kernel<<<(N * 32 + 255) / 256, 256, 0, stream>>>(hA, N * 32);
    // layer 2
    gemm_nn<<<gblocks, 256, 0, stream>>>(hA, W2, y, N);
    agg_init<<<(N * 32 + 255) / 256, 256, 0, stream>>>(y, dinv, b2, hB, N);
    agg_edges<<<(E * 32 + 255) / 256, 256, 0, stream>>>(y, ei, dinv, hB, E);
    relu_kernel<<<(N * 32 + 255) / 256, 256, 0, stream>>>(hB, N * 32);
    // LSTM input projection
    gemm_nt_xg<<<dim3(gblocks, 4), 256, 0, stream>>>(hB, w_ih, b_ih, b_hh, xg, N);
    // sequential LSTM (single CU — the critical path)
    lstm_kernel<<<1, 1024, 0, stream>>>(xg, whp, hs, N);
    // final projection
    fc_kernel<<<(N + 255) / 256, 256, 0, stream>>>(hs, w_fc, b_fc, (float*)d_out, N);
}